// Round 1
// 437.258 us; speedup vs baseline: 1.0104x; 1.0104x over previous
//
#include <hip/hip_runtime.h>
#include <hip/hip_bf16.h>

// RetinaNet loss (focal + smooth-L1) for B=8, A=120000, C=80, M=32.
// R5: in-wave software pipeline for the cls stream.
//   - __syncthreads on gfx950 drains vmcnt(0); R4 issued zero cls loads
//     before the phase-1 barrier, so each wave stalled cold into phase 2.
//     Now the first 5 float4s are issued BEFORE the IOU loop (independent of
//     s_meta) and complete for free under ~770 cycles of phase-1 VALU.
//   - Phase 2 is an explicit 2x5 register pipeline (full unroll, static
//     indices only -> stays in VGPRs, no scratch).
//   - Two staging barriers merged into one (s_area recomputed from global).
//   - Nontemporal loads on the 307 MB zero-reuse cls stream.
// Timed-graph note: ~369 us of the measured dur is 2x harness workspace
// re-poison fills (1.23 GB each @6.6 TB/s) -- not addressable from here.
// Kernel floor: ~322 MB mandatory traffic ~= 51 us @ 6.3 TB/s.

#define CLS 80
#define F4_PER_ANCHOR (CLS / 4)   // 20
#define MAXM 32
#define APB 256                   // anchors per block

typedef float f32x4 __attribute__((ext_vector_type(4)));

__global__ void __launch_bounds__(256)
fused_kernel(const float* __restrict__ anchors,   // B*A*4
             const float* __restrict__ ann,       // B*M*5
             const float* __restrict__ out_reg,   // B*A*4
             const float* __restrict__ cls,       // B*A*C
             const int*   __restrict__ image_shape,
             float* __restrict__ part,            // 3 floats per block: cls,reg,cnt
             int A) {
    __shared__ float s_ann[MAXM * 5];
    __shared__ float s_area[MAXM];
    __shared__ int   s_meta[APB];    // -2 invalid, -1 valid-neg, 0..79 pos class
    __shared__ float s_red[4][3];

    const int b   = blockIdx.y;
    const int tid = threadIdx.x;
    const int a0  = blockIdx.x * APB;
    const int a   = a0 + tid;
    const int nA  = min(APB, A - a0);
    const bool full = (nA == APB);

    const size_t idx = (size_t)b * A + a;

    // hoisted anchor load: latency hides under staging + barrier
    f32x4 an = {0.0f, 0.0f, 0.0f, 0.0f};
    if (a < A) an = ((const f32x4*)anchors)[idx];

    const float* annb = ann + (size_t)b * MAXM * 5;
    if (tid < MAXM * 5) s_ann[tid] = annb[tid];
    if (tid < MAXM) {
        // straight from global (L1-hot) so one barrier suffices
        const float x1 = annb[tid*5+0], y1 = annb[tid*5+1];
        const float x2 = annb[tid*5+2], y2 = annb[tid*5+3];
        s_area[tid] = (x2 - x1) * (y2 - y1);
    }
    __syncthreads();

    // ---- issue first cls load group BEFORE phase-1 compute ----
    const f32x4* cls4 = (const f32x4*)cls + ((size_t)b * A + a0) * F4_PER_ANCHOR;
    f32x4 pipe[2][5];
    if (full) {
        #pragma unroll
        for (int u = 0; u < 5; ++u)
            pipe[0][u] = __builtin_nontemporal_load(cls4 + tid + u * APB);
    }

    // ---- phase 1: anchor assignment (one thread = one anchor) ----
    float regv = 0.0f, cntv = 0.0f;
    if (a < A) {
        const float area_a = (an[2] - an[0]) * (an[3] - an[1]);

        // division-free argmax: iou_j > iou_best <=> inter_j*union_b > inter_b*union_j
        float inter_b = 0.0f, union_b = 1.0f;
        int best = 0;
        #pragma unroll
        for (int j = 0; j < MAXM; ++j) {
            const float bx1 = s_ann[j*5+0], by1 = s_ann[j*5+1];
            const float bx2 = s_ann[j*5+2], by2 = s_ann[j*5+3];
            const float iw = fmaxf(fminf(an[2], bx2) - fmaxf(an[0], bx1), 0.0f);
            const float ih = fmaxf(fminf(an[3], by2) - fmaxf(an[1], by1), 0.0f);
            const float inter = iw * ih;
            const float uni = fmaxf(area_a + s_area[j] - inter, 1e-8f);
            if (inter * union_b > inter_b * uni) {   // strict > == jnp.argmax first-max
                inter_b = inter; union_b = uni; best = j;
            }
        }

        const bool pos = (2.0f * inter_b >= union_b);          // iou >= 0.5
        const bool ign = (inter_b > 0.4f * union_b) && !pos;   // iou > 0.4
        const float cx = (an[0] + an[2]) * 0.5f;
        const float cy = (an[1] + an[3]) * 0.5f;
        const bool outside = (cx >= (float)image_shape[1]) || (cy >= (float)image_shape[0]);

        int state = pos ? 1 : (ign ? -1 : 0);
        if (outside) state = -1;

        s_meta[tid] = (state == -1) ? -2
                    : (state == 1) ? (int)s_ann[best*5+4]
                                   : -1;

        if (state == 1) {   // rare (~0.05% of anchors)
            const float aw = an[2] - an[0];
            const float ah = an[3] - an[1];
            const float t0 = ((s_ann[best*5+0] - an[0]) / aw) * 5.0f;  // /0.2
            const float t1 = ((s_ann[best*5+1] - an[1]) / ah) * 5.0f;
            const float t2 = ((s_ann[best*5+2] - an[2]) / aw) * 5.0f;
            const float t3 = ((s_ann[best*5+3] - an[3]) / ah) * 5.0f;
            const f32x4 r = ((const f32x4*)out_reg)[idx];
            const float d0 = fabsf(r[0] - t0), d1 = fabsf(r[1] - t1);
            const float d2 = fabsf(r[2] - t2), d3 = fabsf(r[3] - t3);
            // sigma^2 = 9: d < 1/9 ? 4.5 d^2 : d - 1/18
            float reg = 0.0f;
            reg += (d0 < (1.0f/9.0f)) ? (4.5f*d0*d0) : (d0 - (0.5f/9.0f));
            reg += (d1 < (1.0f/9.0f)) ? (4.5f*d1*d1) : (d1 - (0.5f/9.0f));
            reg += (d2 < (1.0f/9.0f)) ? (4.5f*d2*d2) : (d2 - (0.5f/9.0f));
            reg += (d3 < (1.0f/9.0f)) ? (4.5f*d3*d3) : (d3 - (0.5f/9.0f));
            regv = reg;
            cntv = 1.0f;
        }
    } else {
        s_meta[tid] = -2;
    }
    __syncthreads();   // drains the prefetch group too -> it completed under phase 1

    // ---- phase 2: focal loss, branch-free, 2x5 register pipeline ----
    float clsv = 0.0f;

    auto focal4 = [&](const f32x4 v, const int i) {
        const int al  = (int)((unsigned)i / 20u);    // const-div -> mul_hi
        const int lab = s_meta[al];                  // LDS dword broadcast
        const float valid = (lab == -2) ? 0.0f : 1.0f;
        const int c0 = (i - al * F4_PER_ANCHOR) * 4;
        #pragma unroll
        for (int k = 0; k < 4; ++k) {
            const float p  = fminf(fmaxf(v[k], 1e-4f), 1.0f - 1e-4f);
            const bool is_pos = (lab == c0 + k);     // never true for -1/-2
            const float pt    = is_pos ? (1.0f - p) : p;
            const float scale = (is_pos ? 0.25f : 0.75f) * valid;
            // bce = -log(p) if pos else -log(1-p)  ==  -log(1 - pt)
            clsv += scale * pt * pt * (-__logf(1.0f - pt));
        }
    };

    if (full) {
        #pragma unroll
        for (int g = 0; g < 4; ++g) {
            if (g < 3) {
                #pragma unroll
                for (int u = 0; u < 5; ++u)
                    pipe[(g + 1) & 1][u] =
                        __builtin_nontemporal_load(cls4 + tid + ((g + 1) * 5 + u) * APB);
            }
            #pragma unroll
            for (int u = 0; u < 5; ++u)
                focal4(pipe[g & 1][u], tid + (g * 5 + u) * APB);
        }
    } else {
        const int nf4 = nA * F4_PER_ANCHOR;
        for (int i = tid; i < nf4; i += APB) {
            const f32x4 v = __builtin_nontemporal_load(cls4 + i);
            focal4(v, i);
        }
    }

    // ---- block reduce (all 64 lanes of every wave active) ----
    #pragma unroll
    for (int off = 32; off > 0; off >>= 1) {
        clsv += __shfl_down(clsv, off, 64);
        regv += __shfl_down(regv, off, 64);
        cntv += __shfl_down(cntv, off, 64);
    }
    const int lane = tid & 63, wid = tid >> 6;
    if (lane == 0) { s_red[wid][0] = clsv; s_red[wid][1] = regv; s_red[wid][2] = cntv; }
    __syncthreads();
    if (tid == 0) {
        const int blk = blockIdx.y * gridDim.x + blockIdx.x;
        part[blk*3+0] = s_red[0][0] + s_red[1][0] + s_red[2][0] + s_red[3][0];
        part[blk*3+1] = s_red[0][1] + s_red[1][1] + s_red[2][1] + s_red[3][1];
        part[blk*3+2] = s_red[0][2] + s_red[1][2] + s_red[2][2] + s_red[3][2];
    }
}

__global__ void final_kernel(const float* __restrict__ part, int n_blk,
                             float* __restrict__ out) {
    float cl = 0.0f, r = 0.0f, c = 0.0f;
    for (int i = threadIdx.x; i < n_blk; i += blockDim.x) {
        cl += part[i*3+0];
        r  += part[i*3+1];
        c  += part[i*3+2];
    }
    #pragma unroll
    for (int off = 32; off > 0; off >>= 1) {
        cl += __shfl_down(cl, off, 64);
        r  += __shfl_down(r,  off, 64);
        c  += __shfl_down(c,  off, 64);
    }
    __shared__ float red[16][3];
    const int lane = threadIdx.x & 63, wid = threadIdx.x >> 6;
    if (lane == 0) { red[wid][0] = cl; red[wid][1] = r; red[wid][2] = c; }
    __syncthreads();
    if (threadIdx.x == 0) {
        float cls = 0.0f, rs = 0.0f, cs = 0.0f;
        const int nw = blockDim.x >> 6;
        for (int w = 0; w < nw; ++w) { cls += red[w][0]; rs += red[w][1]; cs += red[w][2]; }
        out[0] = (cls + rs) / fmaxf(cs, 1.0f);
    }
}

extern "C" void kernel_launch(void* const* d_in, const int* in_sizes, int n_in,
                              void* d_out, int out_size, void* d_ws, size_t ws_size,
                              hipStream_t stream) {
    const float* out_reg = (const float*)d_in[0];   // B*A*4
    const float* out_cls = (const float*)d_in[1];   // B*A*C
    const float* ann     = (const float*)d_in[2];   // B*M*5
    const float* anchors = (const float*)d_in[3];   // B*A*4
    const int*   ishape  = (const int*)d_in[4];     // 2
    float* out = (float*)d_out;

    const int B  = in_sizes[2] / (MAXM * 5);        // 8
    const int BA = in_sizes[0] / 4;                 // B*A
    const int A  = BA / B;                          // 120000

    float* part = (float*)d_ws;                     // 3 floats per block

    const int gx = (A + APB - 1) / APB;             // 469
    dim3 g1(gx, B);
    fused_kernel<<<g1, APB, 0, stream>>>(anchors, ann, out_reg, out_cls,
                                         ishape, part, A);

    final_kernel<<<1, 1024, 0, stream>>>(part, gx * B, out);
}